// Round 19
// baseline (214.383 us; speedup 1.0000x reference)
//
#include <hip/hip_runtime.h>
#include <math.h>
#include <stdint.h>

typedef _Float16 half8 __attribute__((ext_vector_type(8)));
typedef float f32x4 __attribute__((ext_vector_type(4)));
typedef float fvec4 __attribute__((ext_vector_type(4)));
typedef uint32_t u32x4 __attribute__((ext_vector_type(4)));

#define NN   512
#define SS   64
#define HMID 128
#define MM   64

// ---------------------------------------------------------------------------
// prep_all: hbuf zero + Hi/Hj init (h==0) + GRU weight transpose. One launch.
// ---------------------------------------------------------------------------
__global__ void prep_all_kernel(const float* __restrict__ b,
                                const float* __restrict__ mW1,
                                const float* __restrict__ mb1,
                                const float* __restrict__ W_ih,
                                const float* __restrict__ W_hh,
                                float* __restrict__ hbuf,
                                float* __restrict__ Hi, float* __restrict__ Hj,
                                float* __restrict__ WT_ih,
                                float* __restrict__ WT_hh) {
    int idx = blockIdx.x * 256 + threadIdx.x;
    if (idx < 32768) {
        hbuf[idx] = 0.0f;
    } else if (idx < 32768 + 65536) {
        int j = idx - 32768;
        int node = j >> 7, dm = j & 127;
        float bn = b[node];
        Hi[j] = bn * mW1[129 * HMID + dm];
        Hj[j] = bn * mW1[130 * HMID + dm] + mb1[dm];
    } else if (idx < 32768 + 65536 + 12288) {
        int j = idx - 32768 - 65536;         // 192*64
        int g = j / 64, k = j % 64;
        WT_ih[k * 192 + g] = W_ih[j];
        WT_hh[k * 192 + g] = W_hh[j];
    }
}

// ---------------------------------------------------------------------------
// main (R19 = R18 + distance-2 prefetch): grid 512 = 32 j x 16 ig,
// 16 tiles/block, 2x-unrolled loop with ping-pong register sets A/B:
//   even tile tp  : issue loads(tp+2)->B | GEMM1(buf0) | store A->buf1 | bar
//   odd  tile tp+1: issue loads(tp+3)->A | GEMM1(buf1) | store B->buf0 | bar
// Loads now have a FULL tile iteration to complete before their pre_store.
// ---------------------------------------------------------------------------
__global__ __launch_bounds__(256) void main_step_kernel(
    const float* __restrict__ Hi, const float* __restrict__ Hj,
    const float* __restrict__ J, const float* __restrict__ wJ_g,
    const float* __restrict__ mW2, const float* __restrict__ mb2,
    const float* __restrict__ mW3, float* __restrict__ msg,
    float* __restrict__ partial, int use_partial) {

    __shared__ __align__(16) _Float16 H1h[2][32 * 128];   // 16 KB
    __shared__ __align__(16) _Float16 H1l[2][32 * 128];   // 16 KB

    const int t   = threadIdx.x;
    const int w   = t >> 6;      // wave 0..3
    const int l   = t & 63;
    const int l16 = l & 15;
    const int lg  = l >> 4;      // 0..3

    const int j0 = (blockIdx.x & 31) * 16;
    const int ig = blockIdx.x >> 5;          // 0..15, i-range ig*32..+31

    // ---- per-thread block-constant registers: Hj slice, wJ slice ----
    const int lj = t >> 4;       // 0..15  (pre-phase j index)
    const int c  = t & 15;       // 0..15  (pre-phase d-chunk)
    fvec4 hjv0 = *(const fvec4*)&Hj[(j0 + lj) * HMID + c * 8];
    fvec4 hjv1 = *(const fvec4*)&Hj[(j0 + lj) * HMID + c * 8 + 4];
    fvec4 wjv0 = *(const fvec4*)&wJ_g[c * 8];
    fvec4 wjv1 = *(const fvec4*)&wJ_g[c * 8 + 4];

    // ---- W2 fragments (hi+lo f16) in registers ----
    half8 w2h[2][4], w2l[2][4];
    float mb2v[2];
    #pragma unroll
    for (int nb = 0; nb < 2; ++nb) {
        int col = w * 32 + nb * 16 + l16;
        mb2v[nb] = mb2[col];
        #pragma unroll
        for (int kb = 0; kb < 4; ++kb)
            #pragma unroll
            for (int i = 0; i < 8; ++i) {
                int k = kb * 32 + lg * 8 + i;
                float wv = mW2[k * HMID + col];
                _Float16 hh = (_Float16)wv;
                w2h[nb][kb][i] = hh;
                w2l[nb][kb][i] = (_Float16)(wv - (float)hh);
            }
    }

    // hoisted pre-phase LDS write offsets (tile-invariant)
    const int addrW0 = lj * 128 + ((c ^ lj) << 3);
    const int addrW1 = (16 + lj) * 128 + ((c ^ lj) << 3);

    // ---- convert+write helper: regs -> f16 hi/lo -> LDS (swizzled) ----
    auto pre_store = [&](_Float16* __restrict__ dsth,
                         _Float16* __restrict__ dstl,
                         const fvec4& hA0, const fvec4& hA1, float JA,
                         const fvec4& hB0, const fvec4& hB1, float JB) {
        half8 hvh, hvl;
        #pragma unroll
        for (int u = 0; u < 4; ++u) {
            float v0 = hA0[u] + hjv0[u] + JA * wjv0[u];
            float v1 = hA1[u] + hjv1[u] + JA * wjv1[u];
            v0 = v0 > 0.f ? v0 : 0.f;
            v1 = v1 > 0.f ? v1 : 0.f;
            _Float16 g0 = (_Float16)v0, g1 = (_Float16)v1;
            hvh[u]     = g0;
            hvh[u + 4] = g1;
            hvl[u]     = (_Float16)(v0 - (float)g0);
            hvl[u + 4] = (_Float16)(v1 - (float)g1);
        }
        *(half8*)&dsth[addrW0] = hvh;
        *(half8*)&dstl[addrW0] = hvl;
        #pragma unroll
        for (int u = 0; u < 4; ++u) {
            float v0 = hB0[u] + hjv0[u] + JB * wjv0[u];
            float v1 = hB1[u] + hjv1[u] + JB * wjv1[u];
            v0 = v0 > 0.f ? v0 : 0.f;
            v1 = v1 > 0.f ? v1 : 0.f;
            _Float16 g0 = (_Float16)v0, g1 = (_Float16)v1;
            hvh[u]     = g0;
            hvh[u + 4] = g1;
            hvl[u]     = (_Float16)(v0 - (float)g0);
            hvl[u + 4] = (_Float16)(v1 - (float)g1);
        }
        *(half8*)&dsth[addrW1] = hvh;
        *(half8*)&dstl[addrW1] = hvl;
    };

    // ---- GEMM1 + relu + i-sum (reads one LDS buffer, no writes) ----
    float sacc[2][4];
    #pragma unroll
    for (int nb = 0; nb < 2; ++nb)
        #pragma unroll
        for (int q = 0; q < 4; ++q) sacc[nb][q] = 0.f;

    auto gemm1_acc = [&](const _Float16* __restrict__ srch,
                         const _Float16* __restrict__ srcl) {
        f32x4 acc[2][2];
        #pragma unroll
        for (int mb = 0; mb < 2; ++mb)
            #pragma unroll
            for (int nb = 0; nb < 2; ++nb)
                acc[mb][nb] = (f32x4){0.f, 0.f, 0.f, 0.f};
        #pragma unroll
        for (int kb = 0; kb < 4; ++kb) {
            #pragma unroll
            for (int mb = 0; mb < 2; ++mb) {
                int row = mb * 16 + l16;
                int base = row * 128 + (((kb * 4 + lg) ^ l16) << 3);
                half8 ah = *(const half8*)&srch[base];
                half8 al = *(const half8*)&srcl[base];
                #pragma unroll
                for (int nb = 0; nb < 2; ++nb) {
                    acc[mb][nb] = __builtin_amdgcn_mfma_f32_16x16x32_f16(
                        ah, w2h[nb][kb], acc[mb][nb], 0, 0, 0);
                    acc[mb][nb] = __builtin_amdgcn_mfma_f32_16x16x32_f16(
                        al, w2h[nb][kb], acc[mb][nb], 0, 0, 0);
                    acc[mb][nb] = __builtin_amdgcn_mfma_f32_16x16x32_f16(
                        ah, w2l[nb][kb], acc[mb][nb], 0, 0, 0);
                }
            }
        }
        #pragma unroll
        for (int mb = 0; mb < 2; ++mb)
            #pragma unroll
            for (int nb = 0; nb < 2; ++nb)
                #pragma unroll
                for (int q = 0; q < 4; ++q) {
                    float v = acc[mb][nb][q] + mb2v[nb];
                    sacc[nb][q] += (v > 0.f ? v : 0.f);
                }
    };

    // ---- prefetch register sets A and B ----
    fvec4 Aa0, Aa1, Ab0, Ab1; float AJ0 = 0.f, AJ1 = 0.f;
    fvec4 Ba0, Ba1, Bb0, Bb1; float BJ0 = 0.f, BJ1 = 0.f;

    // ---- prologue: stage tile 0 directly; issue loads for tile 1 -> A ----
    {
        int i0 = ig * 32;
        float JA = J[i0 * NN + j0 + lj];
        float JB = J[(i0 + 1) * NN + j0 + lj];
        fvec4 a0 = *(const fvec4*)&Hi[i0 * HMID + c * 8];
        fvec4 a1 = *(const fvec4*)&Hi[i0 * HMID + c * 8 + 4];
        fvec4 b0 = *(const fvec4*)&Hi[(i0 + 1) * HMID + c * 8];
        fvec4 b1 = *(const fvec4*)&Hi[(i0 + 1) * HMID + c * 8 + 4];
        pre_store(H1h[0], H1l[0], a0, a1, JA, b0, b1, JB);
        int i1 = i0 + 2;
        AJ0 = J[i1 * NN + j0 + lj];
        AJ1 = J[(i1 + 1) * NN + j0 + lj];
        Aa0 = *(const fvec4*)&Hi[i1 * HMID + c * 8];
        Aa1 = *(const fvec4*)&Hi[i1 * HMID + c * 8 + 4];
        Ab0 = *(const fvec4*)&Hi[(i1 + 1) * HMID + c * 8];
        Ab1 = *(const fvec4*)&Hi[(i1 + 1) * HMID + c * 8 + 4];
    }
    __syncthreads();

    #pragma unroll 1
    for (int tp = 0; tp < 16; tp += 2) {
        // ======== even tile tp: buf0; loads(tp+2)->B; store A->buf1 ========
        if (tp + 2 < 16) {
            int i0 = (ig * 16 + tp + 2) * 2;
            BJ0 = J[i0 * NN + j0 + lj];
            BJ1 = J[(i0 + 1) * NN + j0 + lj];
            Ba0 = *(const fvec4*)&Hi[i0 * HMID + c * 8];
            Ba1 = *(const fvec4*)&Hi[i0 * HMID + c * 8 + 4];
            Bb0 = *(const fvec4*)&Hi[(i0 + 1) * HMID + c * 8];
            Bb1 = *(const fvec4*)&Hi[(i0 + 1) * HMID + c * 8 + 4];
        }
        gemm1_acc(H1h[0], H1l[0]);
        pre_store(H1h[1], H1l[1], Aa0, Aa1, AJ0, Ab0, Ab1, AJ1);
        __syncthreads();

        // ======== odd tile tp+1: buf1; loads(tp+3)->A; store B->buf0 =======
        if (tp + 3 < 16) {
            int i0 = (ig * 16 + tp + 3) * 2;
            AJ0 = J[i0 * NN + j0 + lj];
            AJ1 = J[(i0 + 1) * NN + j0 + lj];
            Aa0 = *(const fvec4*)&Hi[i0 * HMID + c * 8];
            Aa1 = *(const fvec4*)&Hi[i0 * HMID + c * 8 + 4];
            Ab0 = *(const fvec4*)&Hi[(i0 + 1) * HMID + c * 8];
            Ab1 = *(const fvec4*)&Hi[(i0 + 1) * HMID + c * 8 + 4];
        }
        gemm1_acc(H1h[1], H1l[1]);
        if (tp + 2 < 16)
            pre_store(H1h[0], H1l[0], Ba0, Ba1, BJ0, Bb0, Bb1, BJ1);
        __syncthreads();
    }

    // ---- mini-GEMM: msg_tile(16x64) = S(16x128) @ W3(128x64) ----
    uint32_t* S32 = (uint32_t*)&H1h[0][0];   // 16x128 u32 = 8 KB (buf0 free)
    #pragma unroll
    for (int nb = 0; nb < 2; ++nb)
        #pragma unroll
        for (int q = 0; q < 4; ++q) {
            int j = lg * 4 + q;
            int colc = w * 32 + nb * 16 + l16;
            float s = sacc[nb][q];
            _Float16 hh = (_Float16)s;
            _Float16 ll = (_Float16)(s - (float)hh);
            uint16_t uh = __builtin_bit_cast(uint16_t, hh);
            uint16_t ul = __builtin_bit_cast(uint16_t, ll);
            S32[j * 128 + (colc ^ ((j & 7) << 2))] =
                (uint32_t)uh | ((uint32_t)ul << 16);
        }
    // W3 fragments (loaded once, after W2 regs are dead)
    half8 w3h_[4], w3l_[4];
    {
        int col = w * 16 + l16;
        #pragma unroll
        for (int kb = 0; kb < 4; ++kb)
            #pragma unroll
            for (int i = 0; i < 8; ++i) {
                int k = kb * 32 + lg * 8 + i;
                float wv = mW3[k * MM + col];
                _Float16 hh = (_Float16)wv;
                w3h_[kb][i] = hh;
                w3l_[kb][i] = (_Float16)(wv - (float)hh);
            }
    }
    __syncthreads();

    f32x4 accD = (f32x4){0.f, 0.f, 0.f, 0.f};
    #pragma unroll
    for (int kb = 0; kb < 4; ++kb) {
        int row = l16;
        int sw = (row & 7) << 2;
        int cc = kb * 32 + lg * 8;
        const uint32_t* bp = &S32[row * 128];
        u32x4 A = *(const u32x4*)&bp[cc ^ sw];
        u32x4 B = *(const u32x4*)&bp[(cc + 4) ^ sw];
        union { uint32_t wd[4]; half8 hv; } Ah, Al;
        Ah.wd[0] = __builtin_amdgcn_perm(A[1], A[0], 0x05040100u);
        Ah.wd[1] = __builtin_amdgcn_perm(A[3], A[2], 0x05040100u);
        Ah.wd[2] = __builtin_amdgcn_perm(B[1], B[0], 0x05040100u);
        Ah.wd[3] = __builtin_amdgcn_perm(B[3], B[2], 0x05040100u);
        Al.wd[0] = __builtin_amdgcn_perm(A[1], A[0], 0x07060302u);
        Al.wd[1] = __builtin_amdgcn_perm(A[3], A[2], 0x07060302u);
        Al.wd[2] = __builtin_amdgcn_perm(B[1], B[0], 0x07060302u);
        Al.wd[3] = __builtin_amdgcn_perm(B[3], B[2], 0x07060302u);
        accD = __builtin_amdgcn_mfma_f32_16x16x32_f16(Ah.hv, w3h_[kb], accD,
                                                      0, 0, 0);
        accD = __builtin_amdgcn_mfma_f32_16x16x32_f16(Al.hv, w3h_[kb], accD,
                                                      0, 0, 0);
        accD = __builtin_amdgcn_mfma_f32_16x16x32_f16(Ah.hv, w3l_[kb], accD,
                                                      0, 0, 0);
    }

    // ---- store: C[row=lg*4+q -> j][col=l16 -> m=w*16+l16] ----
    {
        int m = w * 16 + l16;
        #pragma unroll
        for (int q = 0; q < 4; ++q) {
            int j = j0 + lg * 4 + q;
            if (use_partial)
                partial[ig * (NN * MM) + j * MM + m] = accD[q];
            else
                atomicAdd(&msg[j * MM + m], accD[q]);
        }
    }
}

// ---------------------------------------------------------------------------
// GRU update + next-step Hi/Hj; on the last step, fused readout instead.
// 256 threads per node, 512 blocks. Reads 16 per-ig partials.
// ---------------------------------------------------------------------------
__global__ __launch_bounds__(256) void gru_kernel(
    float* __restrict__ msg, const float* __restrict__ partial,
    const float* __restrict__ mb3,
    const float* __restrict__ WT_ih, const float* __restrict__ b_ih,
    const float* __restrict__ WT_hh, const float* __restrict__ b_hh,
    float* __restrict__ h, const float* __restrict__ bvec,
    const float* __restrict__ mW1, const float* __restrict__ mb1,
    float* __restrict__ Hi, float* __restrict__ Hj, int lastStep,
    int use_partial,
    const float* __restrict__ rW1, const float* __restrict__ rb1,
    const float* __restrict__ rW2, const float* __restrict__ rb2,
    const float* __restrict__ rW3, const float* __restrict__ rb3,
    float* __restrict__ out) {

    __shared__ float xb[64], hb[64], hnb[64];
    __shared__ float red[4][6][64];
    __shared__ float redx[4][64];
    __shared__ float o1[128], o2[128];
    int t = threadIdx.x;
    int d = t & 63;
    int p = t >> 6;              // 0..3
    int node = blockIdx.x;

    if (use_partial) {
        float s = 0.f;
        #pragma unroll
        for (int g = 0; g < 4; ++g)
            s += partial[(p * 4 + g) * (NN * MM) + node * MM + d];
        redx[p][d] = s;
    }
    __syncthreads();

    if (p == 0) {
        float x;
        if (use_partial) {
            x = redx[0][d] + redx[1][d] + redx[2][d] + redx[3][d]
                + 512.0f * mb3[d];
        } else {
            x = msg[node * MM + d] + 512.0f * mb3[d];
            msg[node * MM + d] = 0.0f;          // pre-zero for next step
        }
        xb[d] = x;
        hb[d] = h[node * SS + d];
    }
    __syncthreads();

    {
        float s0 = 0.f, s1 = 0.f, s2 = 0.f, s3 = 0.f, s4 = 0.f, s5 = 0.f;
        int k0 = p * 16;
        for (int kk = 0; kk < 16; ++kk) {
            int k = k0 + kk;
            float xk = xb[k], hk = hb[k];
            const float* wi = &WT_ih[k * 192];
            const float* wh = &WT_hh[k * 192];
            s0 += wi[d] * xk;
            s1 += wi[64 + d] * xk;
            s2 += wi[128 + d] * xk;
            s3 += wh[d] * hk;
            s4 += wh[64 + d] * hk;
            s5 += wh[128 + d] * hk;
        }
        red[p][0][d] = s0; red[p][1][d] = s1; red[p][2][d] = s2;
        red[p][3][d] = s3; red[p][4][d] = s4; red[p][5][d] = s5;
    }
    __syncthreads();

    if (p == 0) {
        float gxr = b_ih[d]       + red[0][0][d] + red[1][0][d] + red[2][0][d] + red[3][0][d];
        float gxz = b_ih[64 + d]  + red[0][1][d] + red[1][1][d] + red[2][1][d] + red[3][1][d];
        float gxn = b_ih[128 + d] + red[0][2][d] + red[1][2][d] + red[2][2][d] + red[3][2][d];
        float ghr = b_hh[d]       + red[0][3][d] + red[1][3][d] + red[2][3][d] + red[3][3][d];
        float ghz = b_hh[64 + d]  + red[0][4][d] + red[1][4][d] + red[2][4][d] + red[3][4][d];
        float ghn = b_hh[128 + d] + red[0][5][d] + red[1][5][d] + red[2][5][d] + red[3][5][d];
        float r = 1.f / (1.f + expf(-(gxr + ghr)));
        float z = 1.f / (1.f + expf(-(gxz + ghz)));
        float nc = tanhf(gxn + r * ghn);
        float hnew = (1.f - z) * nc + z * hb[d];
        h[node * SS + d] = hnew;
        hnb[d] = hnew;
    }
    __syncthreads();

    if (!lastStep) {
        int dm = t & 127;
        int half = t >> 7;       // 0: Hi, 1: Hj
        float bn = bvec[node];
        if (half == 0) {
            float ai = bn * mW1[129 * HMID + dm];
            for (int k = 0; k < 64; ++k)
                ai += hnb[k] * mW1[k * HMID + dm];
            Hi[node * HMID + dm] = ai;
        } else {
            float aj = bn * mW1[130 * HMID + dm] + mb1[dm];
            for (int k = 0; k < 64; ++k)
                aj += hnb[k] * mW1[(64 + k) * HMID + dm];
            Hj[node * HMID + dm] = aj;
        }
    } else {
        // ---- fused readout: relu(h@rW1)->relu(@rW2)->@rW3->softmax(2) ----
        if (t < 64) {
            for (int dd = 0; dd < 2; ++dd) {
                int dm = d + dd * 64;
                float a = rb1[dm];
                for (int k = 0; k < 64; ++k) a += hnb[k] * rW1[k * 128 + dm];
                o1[dm] = a > 0.f ? a : 0.f;
            }
        }
        __syncthreads();
        if (t < 64) {
            for (int dd = 0; dd < 2; ++dd) {
                int dm = d + dd * 64;
                float a = rb2[dm];
                for (int k = 0; k < 128; ++k) a += o1[k] * rW2[k * 128 + dm];
                o2[dm] = a > 0.f ? a : 0.f;
            }
        }
        __syncthreads();
        if (t < 64) {
            float p0 = 0.f, p1 = 0.f;
            for (int dd = 0; dd < 2; ++dd) {
                int k = d + dd * 64;
                p0 += o2[k] * rW3[k * 2 + 0];
                p1 += o2[k] * rW3[k * 2 + 1];
            }
            for (int off = 32; off; off >>= 1) {
                p0 += __shfl_xor(p0, off);
                p1 += __shfl_xor(p1, off);
            }
            if (d == 0) {
                p0 += rb3[0];
                p1 += rb3[1];
                float m = fmaxf(p0, p1);
                float e0 = expf(p0 - m), e1 = expf(p1 - m);
                float s = e0 + e1;
                out[node * 2 + 0] = e0 / s;
                out[node * 2 + 1] = e1 / s;
            }
        }
    }
}

// ---------------------------------------------------------------------------
extern "C" void kernel_launch(void* const* d_in, const int* in_sizes, int n_in,
                              void* d_out, int out_size, void* d_ws,
                              size_t ws_size, hipStream_t stream) {
    const float* J    = (const float*)d_in[0];
    const float* b    = (const float*)d_in[1];
    const float* mW1  = (const float*)d_in[2];
    const float* mb1  = (const float*)d_in[3];
    const float* mW2  = (const float*)d_in[4];
    const float* mb2  = (const float*)d_in[5];
    const float* mW3  = (const float*)d_in[6];
    const float* mb3  = (const float*)d_in[7];
    const float* W_ih = (const float*)d_in[8];
    const float* b_ih = (const float*)d_in[9];
    const float* W_hh = (const float*)d_in[10];
    const float* b_hh = (const float*)d_in[11];
    const float* rW1  = (const float*)d_in[12];
    const float* rb1  = (const float*)d_in[13];
    const float* rW2  = (const float*)d_in[14];
    const float* rb2  = (const float*)d_in[15];
    const float* rW3  = (const float*)d_in[16];
    const float* rb3  = (const float*)d_in[17];
    float* out = (float*)d_out;

    float* ws    = (float*)d_ws;
    float* hbuf  = ws;                    // 512*64      = 32768 f
    float* msg   = ws + 32768;            // 512*64      = 32768 f
    float* Hi    = ws + 65536;            // 512*128     = 65536 f
    float* Hj    = ws + 131072;           // 512*128     = 65536 f
    float* WT_ih = ws + 196608;           // 64*192      = 12288 f
    float* WT_hh = ws + 208896;           // 64*192      = 12288 f
    float* partial = ws + 221184;         // 16*512*64   = 524288 f
    size_t need = (221184 + 524288) * sizeof(float);
    int use_partial = (ws_size >= need) ? 1 : 0;

    if (!use_partial)
        hipMemsetAsync(msg, 0, NN * MM * sizeof(float), stream);
    prep_all_kernel<<<432, 256, 0, stream>>>(b, mW1, mb1, W_ih, W_hh,
                                             hbuf, Hi, Hj, WT_ih, WT_hh);

    for (int s = 0; s < 5; ++s) {
        main_step_kernel<<<512, 256, 0, stream>>>(Hi, Hj, J, mW1 + 128 * HMID,
                                                  mW2, mb2, mW3, msg,
                                                  partial, use_partial);
        gru_kernel<<<512, 256, 0, stream>>>(msg, partial, mb3, WT_ih, b_ih,
                                            WT_hh, b_hh, hbuf, b, mW1, mb1,
                                            Hi, Hj, s == 4, use_partial,
                                            rW1, rb1, rW2, rb2, rW3, rb3, out);
    }
}

// Round 20
// 175.552 us; speedup vs baseline: 1.2212x; 1.2212x over previous
//
#include <hip/hip_runtime.h>
#include <math.h>
#include <stdint.h>

typedef _Float16 half8 __attribute__((ext_vector_type(8)));
typedef float f32x4 __attribute__((ext_vector_type(4)));
typedef float fvec4 __attribute__((ext_vector_type(4)));
typedef uint32_t u32x4 __attribute__((ext_vector_type(4)));

#define NN   512
#define SS   64
#define HMID 128
#define MM   64

// ---------------------------------------------------------------------------
// prep_all: hbuf zero + Hi/Hj init (h==0) + GRU weight transpose. One launch.
// ---------------------------------------------------------------------------
__global__ void prep_all_kernel(const float* __restrict__ b,
                                const float* __restrict__ mW1,
                                const float* __restrict__ mb1,
                                const float* __restrict__ W_ih,
                                const float* __restrict__ W_hh,
                                float* __restrict__ hbuf,
                                float* __restrict__ Hi, float* __restrict__ Hj,
                                float* __restrict__ WT_ih,
                                float* __restrict__ WT_hh) {
    int idx = blockIdx.x * 256 + threadIdx.x;
    if (idx < 32768) {
        hbuf[idx] = 0.0f;
    } else if (idx < 32768 + 65536) {
        int j = idx - 32768;
        int node = j >> 7, dm = j & 127;
        float bn = b[node];
        Hi[j] = bn * mW1[129 * HMID + dm];
        Hj[j] = bn * mW1[130 * HMID + dm] + mb1[dm];
    } else if (idx < 32768 + 65536 + 12288) {
        int j = idx - 32768 - 65536;         // 192*64
        int g = j / 64, k = j % 64;
        WT_ih[k * 192 + g] = W_ih[j];
        WT_hh[k * 192 + g] = W_hh[j];
    }
}

// ---------------------------------------------------------------------------
// main (R20 = R18 verbatim, session champion at 176.1 us):
// grid 512 = 32 j-blocks x 16 i-groups, 16 tiles/block. Per tile —
//   1) issue Hi/J(t+1) global loads -> REGISTERS   (T14 async-STAGE split)
//   2) GEMM1(t): LDS reads + 48 MFMA
//   3) relu + i-sum into sacc regs
//   4) convert + LDS-write pre(t+1)   (vmcnt wait lands here, post-GEMM)
//   5) barrier
// VGPR stays at 100 (< the 128 HW quantum — R19 showed crossing it halves
// residency). i-sum hoisted before W3: msg[j] = (sum_i relu(H2)) @ W3.
// ---------------------------------------------------------------------------
__global__ __launch_bounds__(256) void main_step_kernel(
    const float* __restrict__ Hi, const float* __restrict__ Hj,
    const float* __restrict__ J, const float* __restrict__ wJ_g,
    const float* __restrict__ mW2, const float* __restrict__ mb2,
    const float* __restrict__ mW3, float* __restrict__ msg,
    float* __restrict__ partial, int use_partial) {

    __shared__ __align__(16) _Float16 H1h[2][32 * 128];   // 16 KB
    __shared__ __align__(16) _Float16 H1l[2][32 * 128];   // 16 KB

    const int t   = threadIdx.x;
    const int w   = t >> 6;      // wave 0..3
    const int l   = t & 63;
    const int l16 = l & 15;
    const int lg  = l >> 4;      // 0..3

    const int j0 = (blockIdx.x & 31) * 16;
    const int ig = blockIdx.x >> 5;          // 0..15, i-range ig*32..+31

    // ---- per-thread block-constant registers: Hj slice, wJ slice ----
    const int lj = t >> 4;       // 0..15  (pre-phase j index)
    const int c  = t & 15;       // 0..15  (pre-phase d-chunk)
    fvec4 hjv0 = *(const fvec4*)&Hj[(j0 + lj) * HMID + c * 8];
    fvec4 hjv1 = *(const fvec4*)&Hj[(j0 + lj) * HMID + c * 8 + 4];
    fvec4 wjv0 = *(const fvec4*)&wJ_g[c * 8];
    fvec4 wjv1 = *(const fvec4*)&wJ_g[c * 8 + 4];

    // ---- W2 fragments (hi+lo f16) in registers ----
    half8 w2h[2][4], w2l[2][4];
    float mb2v[2];
    #pragma unroll
    for (int nb = 0; nb < 2; ++nb) {
        int col = w * 32 + nb * 16 + l16;
        mb2v[nb] = mb2[col];
        #pragma unroll
        for (int kb = 0; kb < 4; ++kb)
            #pragma unroll
            for (int i = 0; i < 8; ++i) {
                int k = kb * 32 + lg * 8 + i;
                float wv = mW2[k * HMID + col];
                _Float16 hh = (_Float16)wv;
                w2h[nb][kb][i] = hh;
                w2l[nb][kb][i] = (_Float16)(wv - (float)hh);
            }
    }

    // hoisted pre-phase LDS write offsets (tile-invariant)
    const int addrW0 = lj * 128 + ((c ^ lj) << 3);
    const int addrW1 = (16 + lj) * 128 + ((c ^ lj) << 3);

    // ---- convert+write helper: regs -> f16 hi/lo -> LDS (swizzled) ----
    auto pre_store = [&](_Float16* __restrict__ dsth,
                         _Float16* __restrict__ dstl,
                         const fvec4& hA0, const fvec4& hA1, float JA,
                         const fvec4& hB0, const fvec4& hB1, float JB) {
        half8 hvh, hvl;
        #pragma unroll
        for (int u = 0; u < 4; ++u) {
            float v0 = hA0[u] + hjv0[u] + JA * wjv0[u];
            float v1 = hA1[u] + hjv1[u] + JA * wjv1[u];
            v0 = v0 > 0.f ? v0 : 0.f;
            v1 = v1 > 0.f ? v1 : 0.f;
            _Float16 g0 = (_Float16)v0, g1 = (_Float16)v1;
            hvh[u]     = g0;
            hvh[u + 4] = g1;
            hvl[u]     = (_Float16)(v0 - (float)g0);
            hvl[u + 4] = (_Float16)(v1 - (float)g1);
        }
        *(half8*)&dsth[addrW0] = hvh;
        *(half8*)&dstl[addrW0] = hvl;
        #pragma unroll
        for (int u = 0; u < 4; ++u) {
            float v0 = hB0[u] + hjv0[u] + JB * wjv0[u];
            float v1 = hB1[u] + hjv1[u] + JB * wjv1[u];
            v0 = v0 > 0.f ? v0 : 0.f;
            v1 = v1 > 0.f ? v1 : 0.f;
            _Float16 g0 = (_Float16)v0, g1 = (_Float16)v1;
            hvh[u]     = g0;
            hvh[u + 4] = g1;
            hvl[u]     = (_Float16)(v0 - (float)g0);
            hvl[u + 4] = (_Float16)(v1 - (float)g1);
        }
        *(half8*)&dsth[addrW1] = hvh;
        *(half8*)&dstl[addrW1] = hvl;
    };

    // ---- prologue: tile 0 staged the simple way (load+store fused) ----
    {
        int i0 = ig * 32;
        float JA = J[i0 * NN + j0 + lj];
        float JB = J[(i0 + 1) * NN + j0 + lj];
        fvec4 a0 = *(const fvec4*)&Hi[i0 * HMID + c * 8];
        fvec4 a1 = *(const fvec4*)&Hi[i0 * HMID + c * 8 + 4];
        fvec4 b0 = *(const fvec4*)&Hi[(i0 + 1) * HMID + c * 8];
        fvec4 b1 = *(const fvec4*)&Hi[(i0 + 1) * HMID + c * 8 + 4];
        pre_store(H1h[0], H1l[0], a0, a1, JA, b0, b1, JB);
    }
    __syncthreads();

    // S accumulator: S[j = lg*4+q][col = w*32+nb*16+l16], f32, in registers
    float sacc[2][4];
    #pragma unroll
    for (int nb = 0; nb < 2; ++nb)
        #pragma unroll
        for (int q = 0; q < 4; ++q) sacc[nb][q] = 0.f;

    for (int tt = 0; tt < 16; ++tt) {
        const _Float16* srch = H1h[tt & 1];
        const _Float16* srcl = H1l[tt & 1];

        // ---- 1) issue next-tile global loads into registers ----
        fvec4 pa0, pa1, pb0, pb1;
        float pJA = 0.f, pJB = 0.f;
        if (tt < 15) {
            int i0 = (ig * 16 + tt + 1) * 2;
            pJA = J[i0 * NN + j0 + lj];
            pJB = J[(i0 + 1) * NN + j0 + lj];
            pa0 = *(const fvec4*)&Hi[i0 * HMID + c * 8];
            pa1 = *(const fvec4*)&Hi[i0 * HMID + c * 8 + 4];
            pb0 = *(const fvec4*)&Hi[(i0 + 1) * HMID + c * 8];
            pb1 = *(const fvec4*)&Hi[(i0 + 1) * HMID + c * 8 + 4];
        }

        // ---- 2) GEMM1(t): LDS reads + MFMA (no LDS writes before this) ----
        f32x4 acc[2][2];
        #pragma unroll
        for (int mb = 0; mb < 2; ++mb)
            #pragma unroll
            for (int nb = 0; nb < 2; ++nb)
                acc[mb][nb] = (f32x4){0.f, 0.f, 0.f, 0.f};
        #pragma unroll
        for (int kb = 0; kb < 4; ++kb) {
            #pragma unroll
            for (int mb = 0; mb < 2; ++mb) {
                int row = mb * 16 + l16;
                int base = row * 128 + (((kb * 4 + lg) ^ l16) << 3);
                half8 ah = *(const half8*)&srch[base];
                half8 al = *(const half8*)&srcl[base];
                #pragma unroll
                for (int nb = 0; nb < 2; ++nb) {
                    acc[mb][nb] = __builtin_amdgcn_mfma_f32_16x16x32_f16(
                        ah, w2h[nb][kb], acc[mb][nb], 0, 0, 0);
                    acc[mb][nb] = __builtin_amdgcn_mfma_f32_16x16x32_f16(
                        al, w2h[nb][kb], acc[mb][nb], 0, 0, 0);
                    acc[mb][nb] = __builtin_amdgcn_mfma_f32_16x16x32_f16(
                        ah, w2l[nb][kb], acc[mb][nb], 0, 0, 0);
                }
            }
        }

        // ---- 3) relu + i-sum directly in registers ----
        #pragma unroll
        for (int mb = 0; mb < 2; ++mb)
            #pragma unroll
            for (int nb = 0; nb < 2; ++nb)
                #pragma unroll
                for (int q = 0; q < 4; ++q) {
                    float v = acc[mb][nb][q] + mb2v[nb];
                    sacc[nb][q] += (v > 0.f ? v : 0.f);
                }

        // ---- 4) convert + LDS-write pre(t+1) (vmcnt wait lands here) ----
        if (tt < 15)
            pre_store(H1h[(tt + 1) & 1], H1l[(tt + 1) & 1],
                      pa0, pa1, pJA, pb0, pb1, pJB);
        __syncthreads();
    }

    // ---- mini-GEMM: msg_tile(16x64) = S(16x128) @ W3(128x64) ----
    uint32_t* S32 = (uint32_t*)&H1h[0][0];   // 16x128 u32 = 8 KB (buf0 free)
    #pragma unroll
    for (int nb = 0; nb < 2; ++nb)
        #pragma unroll
        for (int q = 0; q < 4; ++q) {
            int j = lg * 4 + q;
            int colc = w * 32 + nb * 16 + l16;
            float s = sacc[nb][q];
            _Float16 hh = (_Float16)s;
            _Float16 ll = (_Float16)(s - (float)hh);
            uint16_t uh = __builtin_bit_cast(uint16_t, hh);
            uint16_t ul = __builtin_bit_cast(uint16_t, ll);
            S32[j * 128 + (colc ^ ((j & 7) << 2))] =
                (uint32_t)uh | ((uint32_t)ul << 16);
        }
    // W3 fragments (loaded once, after W2 regs are dead)
    half8 w3h_[4], w3l_[4];
    {
        int col = w * 16 + l16;
        #pragma unroll
        for (int kb = 0; kb < 4; ++kb)
            #pragma unroll
            for (int i = 0; i < 8; ++i) {
                int k = kb * 32 + lg * 8 + i;
                float wv = mW3[k * MM + col];
                _Float16 hh = (_Float16)wv;
                w3h_[kb][i] = hh;
                w3l_[kb][i] = (_Float16)(wv - (float)hh);
            }
    }
    __syncthreads();

    f32x4 accD = (f32x4){0.f, 0.f, 0.f, 0.f};
    #pragma unroll
    for (int kb = 0; kb < 4; ++kb) {
        int row = l16;
        int sw = (row & 7) << 2;
        int cc = kb * 32 + lg * 8;
        const uint32_t* bp = &S32[row * 128];
        u32x4 A = *(const u32x4*)&bp[cc ^ sw];
        u32x4 B = *(const u32x4*)&bp[(cc + 4) ^ sw];
        union { uint32_t wd[4]; half8 hv; } Ah, Al;
        Ah.wd[0] = __builtin_amdgcn_perm(A[1], A[0], 0x05040100u);
        Ah.wd[1] = __builtin_amdgcn_perm(A[3], A[2], 0x05040100u);
        Ah.wd[2] = __builtin_amdgcn_perm(B[1], B[0], 0x05040100u);
        Ah.wd[3] = __builtin_amdgcn_perm(B[3], B[2], 0x05040100u);
        Al.wd[0] = __builtin_amdgcn_perm(A[1], A[0], 0x07060302u);
        Al.wd[1] = __builtin_amdgcn_perm(A[3], A[2], 0x07060302u);
        Al.wd[2] = __builtin_amdgcn_perm(B[1], B[0], 0x07060302u);
        Al.wd[3] = __builtin_amdgcn_perm(B[3], B[2], 0x07060302u);
        accD = __builtin_amdgcn_mfma_f32_16x16x32_f16(Ah.hv, w3h_[kb], accD,
                                                      0, 0, 0);
        accD = __builtin_amdgcn_mfma_f32_16x16x32_f16(Al.hv, w3h_[kb], accD,
                                                      0, 0, 0);
        accD = __builtin_amdgcn_mfma_f32_16x16x32_f16(Ah.hv, w3l_[kb], accD,
                                                      0, 0, 0);
    }

    // ---- store: C[row=lg*4+q -> j][col=l16 -> m=w*16+l16] ----
    {
        int m = w * 16 + l16;
        #pragma unroll
        for (int q = 0; q < 4; ++q) {
            int j = j0 + lg * 4 + q;
            if (use_partial)
                partial[ig * (NN * MM) + j * MM + m] = accD[q];
            else
                atomicAdd(&msg[j * MM + m], accD[q]);
        }
    }
}

// ---------------------------------------------------------------------------
// GRU update + next-step Hi/Hj; on the last step, fused readout instead.
// 256 threads per node, 512 blocks. Reads 16 per-ig partials.
// ---------------------------------------------------------------------------
__global__ __launch_bounds__(256) void gru_kernel(
    float* __restrict__ msg, const float* __restrict__ partial,
    const float* __restrict__ mb3,
    const float* __restrict__ WT_ih, const float* __restrict__ b_ih,
    const float* __restrict__ WT_hh, const float* __restrict__ b_hh,
    float* __restrict__ h, const float* __restrict__ bvec,
    const float* __restrict__ mW1, const float* __restrict__ mb1,
    float* __restrict__ Hi, float* __restrict__ Hj, int lastStep,
    int use_partial,
    const float* __restrict__ rW1, const float* __restrict__ rb1,
    const float* __restrict__ rW2, const float* __restrict__ rb2,
    const float* __restrict__ rW3, const float* __restrict__ rb3,
    float* __restrict__ out) {

    __shared__ float xb[64], hb[64], hnb[64];
    __shared__ float red[4][6][64];
    __shared__ float redx[4][64];
    __shared__ float o1[128], o2[128];
    int t = threadIdx.x;
    int d = t & 63;
    int p = t >> 6;              // 0..3
    int node = blockIdx.x;

    if (use_partial) {
        float s = 0.f;
        #pragma unroll
        for (int g = 0; g < 4; ++g)
            s += partial[(p * 4 + g) * (NN * MM) + node * MM + d];
        redx[p][d] = s;
    }
    __syncthreads();

    if (p == 0) {
        float x;
        if (use_partial) {
            x = redx[0][d] + redx[1][d] + redx[2][d] + redx[3][d]
                + 512.0f * mb3[d];
        } else {
            x = msg[node * MM + d] + 512.0f * mb3[d];
            msg[node * MM + d] = 0.0f;          // pre-zero for next step
        }
        xb[d] = x;
        hb[d] = h[node * SS + d];
    }
    __syncthreads();

    {
        float s0 = 0.f, s1 = 0.f, s2 = 0.f, s3 = 0.f, s4 = 0.f, s5 = 0.f;
        int k0 = p * 16;
        for (int kk = 0; kk < 16; ++kk) {
            int k = k0 + kk;
            float xk = xb[k], hk = hb[k];
            const float* wi = &WT_ih[k * 192];
            const float* wh = &WT_hh[k * 192];
            s0 += wi[d] * xk;
            s1 += wi[64 + d] * xk;
            s2 += wi[128 + d] * xk;
            s3 += wh[d] * hk;
            s4 += wh[64 + d] * hk;
            s5 += wh[128 + d] * hk;
        }
        red[p][0][d] = s0; red[p][1][d] = s1; red[p][2][d] = s2;
        red[p][3][d] = s3; red[p][4][d] = s4; red[p][5][d] = s5;
    }
    __syncthreads();

    if (p == 0) {
        float gxr = b_ih[d]       + red[0][0][d] + red[1][0][d] + red[2][0][d] + red[3][0][d];
        float gxz = b_ih[64 + d]  + red[0][1][d] + red[1][1][d] + red[2][1][d] + red[3][1][d];
        float gxn = b_ih[128 + d] + red[0][2][d] + red[1][2][d] + red[2][2][d] + red[3][2][d];
        float ghr = b_hh[d]       + red[0][3][d] + red[1][3][d] + red[2][3][d] + red[3][3][d];
        float ghz = b_hh[64 + d]  + red[0][4][d] + red[1][4][d] + red[2][4][d] + red[3][4][d];
        float ghn = b_hh[128 + d] + red[0][5][d] + red[1][5][d] + red[2][5][d] + red[3][5][d];
        float r = 1.f / (1.f + expf(-(gxr + ghr)));
        float z = 1.f / (1.f + expf(-(gxz + ghz)));
        float nc = tanhf(gxn + r * ghn);
        float hnew = (1.f - z) * nc + z * hb[d];
        h[node * SS + d] = hnew;
        hnb[d] = hnew;
    }
    __syncthreads();

    if (!lastStep) {
        int dm = t & 127;
        int half = t >> 7;       // 0: Hi, 1: Hj
        float bn = bvec[node];
        if (half == 0) {
            float ai = bn * mW1[129 * HMID + dm];
            for (int k = 0; k < 64; ++k)
                ai += hnb[k] * mW1[k * HMID + dm];
            Hi[node * HMID + dm] = ai;
        } else {
            float aj = bn * mW1[130 * HMID + dm] + mb1[dm];
            for (int k = 0; k < 64; ++k)
                aj += hnb[k] * mW1[(64 + k) * HMID + dm];
            Hj[node * HMID + dm] = aj;
        }
    } else {
        // ---- fused readout: relu(h@rW1)->relu(@rW2)->@rW3->softmax(2) ----
        if (t < 64) {
            for (int dd = 0; dd < 2; ++dd) {
                int dm = d + dd * 64;
                float a = rb1[dm];
                for (int k = 0; k < 64; ++k) a += hnb[k] * rW1[k * 128 + dm];
                o1[dm] = a > 0.f ? a : 0.f;
            }
        }
        __syncthreads();
        if (t < 64) {
            for (int dd = 0; dd < 2; ++dd) {
                int dm = d + dd * 64;
                float a = rb2[dm];
                for (int k = 0; k < 128; ++k) a += o1[k] * rW2[k * 128 + dm];
                o2[dm] = a > 0.f ? a : 0.f;
            }
        }
        __syncthreads();
        if (t < 64) {
            float p0 = 0.f, p1 = 0.f;
            for (int dd = 0; dd < 2; ++dd) {
                int k = d + dd * 64;
                p0 += o2[k] * rW3[k * 2 + 0];
                p1 += o2[k] * rW3[k * 2 + 1];
            }
            for (int off = 32; off; off >>= 1) {
                p0 += __shfl_xor(p0, off);
                p1 += __shfl_xor(p1, off);
            }
            if (d == 0) {
                p0 += rb3[0];
                p1 += rb3[1];
                float m = fmaxf(p0, p1);
                float e0 = expf(p0 - m), e1 = expf(p1 - m);
                float s = e0 + e1;
                out[node * 2 + 0] = e0 / s;
                out[node * 2 + 1] = e1 / s;
            }
        }
    }
}

// ---------------------------------------------------------------------------
extern "C" void kernel_launch(void* const* d_in, const int* in_sizes, int n_in,
                              void* d_out, int out_size, void* d_ws,
                              size_t ws_size, hipStream_t stream) {
    const float* J    = (const float*)d_in[0];
    const float* b    = (const float*)d_in[1];
    const float* mW1  = (const float*)d_in[2];
    const float* mb1  = (const float*)d_in[3];
    const float* mW2  = (const float*)d_in[4];
    const float* mb2  = (const float*)d_in[5];
    const float* mW3  = (const float*)d_in[6];
    const float* mb3  = (const float*)d_in[7];
    const float* W_ih = (const float*)d_in[8];
    const float* b_ih = (const float*)d_in[9];
    const float* W_hh = (const float*)d_in[10];
    const float* b_hh = (const float*)d_in[11];
    const float* rW1  = (const float*)d_in[12];
    const float* rb1  = (const float*)d_in[13];
    const float* rW2  = (const float*)d_in[14];
    const float* rb2  = (const float*)d_in[15];
    const float* rW3  = (const float*)d_in[16];
    const float* rb3  = (const float*)d_in[17];
    float* out = (float*)d_out;

    float* ws    = (float*)d_ws;
    float* hbuf  = ws;                    // 512*64      = 32768 f
    float* msg   = ws + 32768;            // 512*64      = 32768 f
    float* Hi    = ws + 65536;            // 512*128     = 65536 f
    float* Hj    = ws + 131072;           // 512*128     = 65536 f
    float* WT_ih = ws + 196608;           // 64*192      = 12288 f
    float* WT_hh = ws + 208896;           // 64*192      = 12288 f
    float* partial = ws + 221184;         // 16*512*64   = 524288 f
    size_t need = (221184 + 524288) * sizeof(float);
    int use_partial = (ws_size >= need) ? 1 : 0;

    if (!use_partial)
        hipMemsetAsync(msg, 0, NN * MM * sizeof(float), stream);
    prep_all_kernel<<<432, 256, 0, stream>>>(b, mW1, mb1, W_ih, W_hh,
                                             hbuf, Hi, Hj, WT_ih, WT_hh);

    for (int s = 0; s < 5; ++s) {
        main_step_kernel<<<512, 256, 0, stream>>>(Hi, Hj, J, mW1 + 128 * HMID,
                                                  mW2, mb2, mW3, msg,
                                                  partial, use_partial);
        gru_kernel<<<512, 256, 0, stream>>>(msg, partial, mb3, WT_ih, b_ih,
                                            WT_hh, b_hh, hbuf, b, mW1, mb1,
                                            Hi, Hj, s == 4, use_partial,
                                            rW1, rb1, rW2, rb2, rW3, rb3, out);
    }
}